// Round 1
// baseline (507.019 us; speedup 1.0000x reference)
//
#include <hip/hip_runtime.h>
#include <stdint.h>

typedef __bf16 bf16;
typedef bf16 bf16x8 __attribute__((ext_vector_type(8)));
typedef bf16 bf16x4 __attribute__((ext_vector_type(4)));
typedef float f32x4 __attribute__((ext_vector_type(4)));

#define MFMA16(a, b, c) __builtin_amdgcn_mfma_f32_16x16x32_bf16(a, b, c, 0, 0, 0)

__device__ __forceinline__ void gll16(const void* g, void* l) {
    __builtin_amdgcn_global_load_lds(
        (const __attribute__((address_space(1))) void*)g,
        (__attribute__((address_space(3))) void*)l, 16, 0, 0);
}

__device__ __forceinline__ float frcp(float x) { return __builtin_amdgcn_rcpf(x); }

__device__ __forceinline__ float bflo(uint32_t u) {
    union { uint32_t i; float f; } x; x.i = u << 16; return x.f;
}
__device__ __forceinline__ float bfhi(uint32_t u) {
    union { uint32_t i; float f; } x; x.i = u & 0xffff0000u; return x.f;
}
__device__ __forceinline__ uint32_t packcv(float c, float v) {
    union { bf16 b[2]; uint32_t u; } p;
    p.b[0] = (bf16)c; p.b[1] = (bf16)v; return p.u;
}

// ---------------- fp32 -> bf16 conversion: X + Whg + Wout ----------------
__global__ __launch_bounds__(256) void conv_kernel(
    const float* __restrict__ X, const float* __restrict__ Whg,
    const float* __restrict__ Wout, bf16* __restrict__ Xbf,
    bf16* __restrict__ Whg_bf, bf16* __restrict__ Wout_bf) {
    int i = blockIdx.x * 256 + threadIdx.x;
    if (i < 8388608) {
        f32x4 v = ((const f32x4*)X)[i];
        ((bf16x4*)Xbf)[i] = __builtin_convertvector(v, bf16x4);
    } else if (i < 8388608 + 131072) {
        int j = i - 8388608;
        f32x4 v = ((const f32x4*)Whg)[j];
        ((bf16x4*)Whg_bf)[j] = __builtin_convertvector(v, bf16x4);
    } else {
        int j = i - (8388608 + 131072);  // < 65536
        f32x4 v = ((const f32x4*)Wout)[j];
        ((bf16x4*)Wout_bf)[j] = __builtin_convertvector(v, bf16x4);
    }
}

// ---------------- GEMM1: hg = x @ W_hg^T, fused sigmoid epilogue -> packed (c,v) ----------------
// BM=256, BN=128, BK=64, 512 threads (8 waves = 4M x 2N), double-buffered LDS,
// issue-early prefetch with counted vmcnt (T3+T4), setprio around MFMA (T5).
// XOR-8 swizzled LDS granules (granule = 16 B = 8 bf16): physical granule for
// (row, c8) is (row*8 + (c8 ^ (row&7))).
__global__ __launch_bounds__(512, 2) void gemm1_kernel(
    const bf16* __restrict__ Xbf, const bf16* __restrict__ W,
    uint32_t* __restrict__ CV) {
    constexpr int K = 512;
    __shared__ bf16 As[2][256 * 64];   // 2 x 32 KB
    __shared__ bf16 Bh[2][128 * 64];   // 2 x 16 KB
    __shared__ bf16 Bg[2][128 * 64];   // 2 x 16 KB   -> 128 KB total

    const int t = threadIdx.x;
    const size_t m0 = (size_t)blockIdx.x * 256;
    const int n0 = blockIdx.y * 128;
    const int w = t >> 6, lane = t & 63;
    const int wm = (w >> 1) * 64, wn = (w & 1) * 64;
    const int r16 = lane & 15, quad = lane >> 4;
    const int sw = r16 & 7;

    f32x4 ah[4][4] = {};
    f32x4 ag[4][4] = {};

    // stage one BK=64 K-slice of A (256x64) + Bh + Bg (128x64 each): 8 gll16/thread
    auto stage = [&](int buf, int k0) {
        #pragma unroll
        for (int r = 0; r < 4; ++r) {
            int g = r * 512 + t;            // A: 2048 granules
            int row = g >> 3;
            int c8 = (g & 7) ^ (row & 7);
            gll16(Xbf + (m0 + row) * K + k0 + c8 * 8, &As[buf][g * 8]);
        }
        #pragma unroll
        for (int r = 0; r < 2; ++r) {
            int g = r * 512 + t;            // B: 1024 granules each
            int row = g >> 3;
            int c8 = (g & 7) ^ (row & 7);
            gll16(W + (size_t)(n0 + row) * K + k0 + c8 * 8, &Bh[buf][g * 8]);
            gll16(W + (size_t)(512 + n0 + row) * K + k0 + c8 * 8, &Bg[buf][g * 8]);
        }
    };

    stage(0, 0);
    #pragma unroll 2
    for (int ks = 0; ks < 8; ++ks) {
        const int cur = ks & 1;
        if (ks < 7) {
            stage(cur ^ 1, (ks + 1) * 64);                 // issue next tile early
            asm volatile("s_waitcnt vmcnt(8)" ::: "memory");  // wait current tile only
        } else {
            asm volatile("s_waitcnt vmcnt(0)" ::: "memory");
        }
        __builtin_amdgcn_s_barrier();      // all waves' current-tile loads landed
        asm volatile("" ::: "memory");
        #pragma unroll
        for (int kk = 0; kk < 2; ++kk) {
            const int kg = kk * 4 + quad;
            bf16x8 af[4], bhf[4], bgf[4];
            #pragma unroll
            for (int i = 0; i < 4; ++i)
                af[i] = *(const bf16x8*)&As[cur][(wm + i * 16 + r16) * 64 + (kg ^ sw) * 8];
            #pragma unroll
            for (int i = 0; i < 4; ++i) {
                bhf[i] = *(const bf16x8*)&Bh[cur][(wn + i * 16 + r16) * 64 + (kg ^ sw) * 8];
                bgf[i] = *(const bf16x8*)&Bg[cur][(wn + i * 16 + r16) * 64 + (kg ^ sw) * 8];
            }
            __builtin_amdgcn_s_setprio(1);
            #pragma unroll
            for (int mi = 0; mi < 4; ++mi)
                #pragma unroll
                for (int ni = 0; ni < 4; ++ni) {
                    ah[mi][ni] = MFMA16(af[mi], bhf[ni], ah[mi][ni]);
                    ag[mi][ni] = MFMA16(af[mi], bgf[ni], ag[mi][ni]);
                }
            __builtin_amdgcn_s_setprio(0);
        }
        asm volatile("" ::: "memory");
        __builtin_amdgcn_s_barrier();      // all reads of buf[cur] done before overwrite
    }

    // epilogue: z = sigmoid(gate); c = 1-z; v = z*g(hidden)
    #pragma unroll
    for (int mi = 0; mi < 4; ++mi)
        #pragma unroll
        for (int ni = 0; ni < 4; ++ni)
            #pragma unroll
            for (int r = 0; r < 4; ++r) {
                size_t row = m0 + wm + mi * 16 + quad * 4 + r;
                int col = n0 + wn + ni * 16 + r16;
                float hid = ah[mi][ni][r], gat = ag[mi][ni][r];
                float z = frcp(1.f + __expf(-gat));     // sigmoid(gate)
                float c = 1.f - z;                      // sigmoid(-gate)
                float gv = hid >= 0.f ? hid + 0.5f : frcp(1.f + __expf(-hid));
                CV[row * 512 + col] = packcv(c, z * gv);
            }
}

// ---------------- scan: h[t] = c[t]*h[t-1] + v[t], chunked 3-phase ----------------
#define NC 64
#define CHUNK 128  // 8192 / NC

__global__ __launch_bounds__(256) void scan1_kernel(
    const uint32_t* __restrict__ CV, float2* __restrict__ agg) {
    int idx = blockIdx.x * 256 + threadIdx.x;  // 8*64*512 = 262144
    int h = idx & 511;
    int ch = (idx >> 9) & (NC - 1);
    int b = idx >> 15;
    const uint32_t* p = CV + (((size_t)b * 8192 + (size_t)ch * CHUNK) * 512 + h);
    float C = 1.f, V = 0.f;
    for (int tt = 0; tt < CHUNK; tt += 8) {
        uint32_t u[8];
        #pragma unroll
        for (int j = 0; j < 8; ++j) u[j] = p[(size_t)(tt + j) * 512];
        #pragma unroll
        for (int j = 0; j < 8; ++j) {
            float c = bflo(u[j]), v = bfhi(u[j]);
            C *= c;
            V = c * V + v;
        }
    }
    agg[idx] = make_float2(C, V);
}

__global__ __launch_bounds__(256) void scan2_kernel(
    const float2* __restrict__ agg, float* __restrict__ h0) {
    int idx = blockIdx.x * 256 + threadIdx.x;  // 4096
    int h = idx & 511;
    int b = idx >> 9;
    float hr = 0.f;
    for (int ch = 0; ch < NC; ++ch) {
        size_t o = ((size_t)b * NC + ch) * 512 + h;
        h0[o] = hr;
        float2 a = agg[o];
        hr = a.x * hr + a.y;
    }
}

__global__ __launch_bounds__(256) void scan3_kernel(
    const uint32_t* __restrict__ CV, const float* __restrict__ h0,
    bf16* __restrict__ Hbf, float* __restrict__ hn) {
    int idx = blockIdx.x * 256 + threadIdx.x;
    int h = idx & 511;
    int ch = (idx >> 9) & (NC - 1);
    int b = idx >> 15;
    size_t base = ((size_t)b * 8192 + (size_t)ch * CHUNK) * 512 + h;
    const uint32_t* p = CV + base;
    bf16* q = Hbf + base;
    float hcur = h0[idx];
    for (int tt = 0; tt < CHUNK; tt += 8) {
        uint32_t u[8];
        #pragma unroll
        for (int j = 0; j < 8; ++j) u[j] = p[(size_t)(tt + j) * 512];
        #pragma unroll
        for (int j = 0; j < 8; ++j) {
            float c = bflo(u[j]), v = bfhi(u[j]);
            hcur = c * hcur + v;
            q[(size_t)(tt + j) * 512] = (bf16)hcur;
        }
    }
    if (ch == NC - 1) hn[b * 512 + h] = hcur;  // fp32 h_n output
}

// ---------------- GEMM2: out = h @ W_out^T (bf16 MFMA, fp32 out) ----------------
// Same pipelined structure as gemm1: BM=256, BN=128, BK=64, dbuf LDS, vmcnt(6).
__global__ __launch_bounds__(512, 2) void gemm2_kernel(
    const bf16* __restrict__ Ah, const bf16* __restrict__ Wo,
    float* __restrict__ Out) {
    constexpr int K = 512;
    __shared__ bf16 As[2][256 * 64];   // 2 x 32 KB
    __shared__ bf16 Bs[2][128 * 64];   // 2 x 16 KB   -> 96 KB total
    const int t = threadIdx.x;
    const size_t m0 = (size_t)blockIdx.x * 256;
    const int n0 = blockIdx.y * 128;
    const int w = t >> 6, lane = t & 63;
    const int wm = (w >> 1) * 64, wn = (w & 1) * 64;
    const int r16 = lane & 15, quad = lane >> 4;
    const int sw = r16 & 7;
    f32x4 acc[4][4] = {};

    auto stage = [&](int buf, int k0) {
        #pragma unroll
        for (int r = 0; r < 4; ++r) {
            int g = r * 512 + t;
            int row = g >> 3;
            int c8 = (g & 7) ^ (row & 7);
            gll16(Ah + (m0 + row) * K + k0 + c8 * 8, &As[buf][g * 8]);
        }
        #pragma unroll
        for (int r = 0; r < 2; ++r) {
            int g = r * 512 + t;
            int row = g >> 3;
            int c8 = (g & 7) ^ (row & 7);
            gll16(Wo + (size_t)(n0 + row) * K + k0 + c8 * 8, &Bs[buf][g * 8]);
        }
    };

    stage(0, 0);
    #pragma unroll 2
    for (int ks = 0; ks < 8; ++ks) {
        const int cur = ks & 1;
        if (ks < 7) {
            stage(cur ^ 1, (ks + 1) * 64);
            asm volatile("s_waitcnt vmcnt(6)" ::: "memory");
        } else {
            asm volatile("s_waitcnt vmcnt(0)" ::: "memory");
        }
        __builtin_amdgcn_s_barrier();
        asm volatile("" ::: "memory");
        #pragma unroll
        for (int kk = 0; kk < 2; ++kk) {
            const int kg = kk * 4 + quad;
            bf16x8 af[4], bff[4];
            #pragma unroll
            for (int i = 0; i < 4; ++i)
                af[i] = *(const bf16x8*)&As[cur][(wm + i * 16 + r16) * 64 + (kg ^ sw) * 8];
            #pragma unroll
            for (int i = 0; i < 4; ++i)
                bff[i] = *(const bf16x8*)&Bs[cur][(wn + i * 16 + r16) * 64 + (kg ^ sw) * 8];
            __builtin_amdgcn_s_setprio(1);
            #pragma unroll
            for (int mi = 0; mi < 4; ++mi)
                #pragma unroll
                for (int ni = 0; ni < 4; ++ni)
                    acc[mi][ni] = MFMA16(af[mi], bff[ni], acc[mi][ni]);
            __builtin_amdgcn_s_setprio(0);
        }
        asm volatile("" ::: "memory");
        __builtin_amdgcn_s_barrier();
    }
    #pragma unroll
    for (int mi = 0; mi < 4; ++mi)
        #pragma unroll
        for (int ni = 0; ni < 4; ++ni)
            #pragma unroll
            for (int r = 0; r < 4; ++r) {
                size_t row = m0 + wm + mi * 16 + quad * 4 + r;
                int col = n0 + wn + ni * 16 + r16;
                Out[row * 512 + col] = acc[mi][ni][r];
            }
}

extern "C" void kernel_launch(void* const* d_in, const int* in_sizes, int n_in,
                              void* d_out, int out_size, void* d_ws, size_t ws_size,
                              hipStream_t stream) {
    const float* x    = (const float*)d_in[0];
    // d_in[1] = is_init (unused by reference)
    const float* Whg  = (const float*)d_in[2];
    const float* Wout = (const float*)d_in[3];
    float* out = (float*)d_out;

    const int M = 8 * 8192;  // 65536

    // Workspace layout (total 206045184 B):
    //   [0, 67108864)           Xbf  (later aliased by Hbf — Xbf dead after gemm1)
    //   [67108864, 68157440)    Whg_bf
    //   [68157440, 68681728)    Wout_bf
    //   [68681728, 202899456)   CV
    //   [202899456, 204996608)  agg
    //   [204996608, 206045184)  h0
    char* ws = (char*)d_ws;
    bf16*     Xbf     = (bf16*)ws;
    bf16*     Hbf     = (bf16*)ws;                 // alias: valid, see ordering
    bf16*     Whg_bf  = (bf16*)(ws + 67108864);
    bf16*     Wout_bf = (bf16*)(ws + 68157440);
    uint32_t* CV      = (uint32_t*)(ws + 68681728);
    float2*   agg     = (float2*)(ws + 202899456);
    float*    h0      = (float*)(ws + 204996608);

    conv_kernel<<<33536, 256, 0, stream>>>(x, Whg, Wout, Xbf, Whg_bf, Wout_bf);

    dim3 g1(M / 256, 4);
    gemm1_kernel<<<g1, 512, 0, stream>>>(Xbf, Whg_bf, CV);

    scan1_kernel<<<(8 * NC * 512) / 256, 256, 0, stream>>>(CV, agg);
    scan2_kernel<<<16, 256, 0, stream>>>(agg, h0);
    scan3_kernel<<<(8 * NC * 512) / 256, 256, 0, stream>>>(CV, h0, Hbf,
                                                           out + (size_t)M * 512);

    dim3 g2(M / 256, 4);
    gemm2_kernel<<<g2, 512, 0, stream>>>(Hbf, Wout_bf, out);
}

// Round 2
// 435.179 us; speedup vs baseline: 1.1651x; 1.1651x over previous
//
#include <hip/hip_runtime.h>
#include <stdint.h>

typedef __bf16 bf16;
typedef bf16 bf16x8 __attribute__((ext_vector_type(8)));
typedef bf16 bf16x4 __attribute__((ext_vector_type(4)));
typedef float f32x4 __attribute__((ext_vector_type(4)));

#define MFMA16(a, b, c) __builtin_amdgcn_mfma_f32_16x16x32_bf16(a, b, c, 0, 0, 0)

__device__ __forceinline__ void gll16(const void* g, void* l) {
    __builtin_amdgcn_global_load_lds(
        (const __attribute__((address_space(1))) void*)g,
        (__attribute__((address_space(3))) void*)l, 16, 0, 0);
}

__device__ __forceinline__ float frcp(float x) { return __builtin_amdgcn_rcpf(x); }

__device__ __forceinline__ float bflo(uint32_t u) {
    union { uint32_t i; float f; } x; x.i = u << 16; return x.f;
}
__device__ __forceinline__ float bfhi(uint32_t u) {
    union { uint32_t i; float f; } x; x.i = u & 0xffff0000u; return x.f;
}
__device__ __forceinline__ uint32_t packcv(float c, float v) {
    union { bf16 b[2]; uint32_t u; } p;
    p.b[0] = (bf16)c; p.b[1] = (bf16)v; return p.u;
}

// ---------------- fp32 -> bf16 conversion: X + Whg + Wout ----------------
__global__ __launch_bounds__(256) void conv_kernel(
    const float* __restrict__ X, const float* __restrict__ Whg,
    const float* __restrict__ Wout, bf16* __restrict__ Xbf,
    bf16* __restrict__ Whg_bf, bf16* __restrict__ Wout_bf) {
    int i = blockIdx.x * 256 + threadIdx.x;
    if (i < 8388608) {
        f32x4 v = ((const f32x4*)X)[i];
        ((bf16x4*)Xbf)[i] = __builtin_convertvector(v, bf16x4);
    } else if (i < 8388608 + 131072) {
        int j = i - 8388608;
        f32x4 v = ((const f32x4*)Whg)[j];
        ((bf16x4*)Whg_bf)[j] = __builtin_convertvector(v, bf16x4);
    } else {
        int j = i - (8388608 + 131072);  // < 65536
        f32x4 v = ((const f32x4*)Wout)[j];
        ((bf16x4*)Wout_bf)[j] = __builtin_convertvector(v, bf16x4);
    }
}

// ---------------- GEMM1: hg = x @ W_hg^T, fused sigmoid epilogue -> packed (c,v) ----------------
// m201-style phase schedule: BM=256, N-tile = 128 cols of h AND g, BK=64,
// 512 threads = 8 waves (4M x 2N, each wave 64x64 of h and of g).
// Double-buffered LDS (128 KB). 4 phases per K-tile:
//   P0: kk0 h (8 ds_read, 16 MFMA)   | stage A1(t+1)
//   P1: kk0 g (4 ds_read, 16 MFMA)   | stage Bh(t+1)
//   P2: kk1 h (8 ds_read, 16 MFMA)   | stage Bg(t+1)
//   P3: kk1 g (4 ds_read, 16 MFMA)   | stage A0(t+2)  <- 1.25 tiles ahead
// Counted waits: vmcnt(4) at P0 (guarantees Bg(t) for P1) and at P3
// (guarantees A+Bh(t+1) for next P0). Never vmcnt(0) in steady state.
// XOR-8 granule swizzle (granule = 16 B): phys granule = row*8 + (c8 ^ (row&7)).
__global__ __launch_bounds__(512, 2) void gemm1_kernel(
    const bf16* __restrict__ Xbf, const bf16* __restrict__ W,
    uint32_t* __restrict__ CV) {
    constexpr int K = 512;
    __shared__ bf16 As[2][256 * 64];   // 2 x 32 KB
    __shared__ bf16 Bh[2][128 * 64];   // 2 x 16 KB
    __shared__ bf16 Bg[2][128 * 64];   // 2 x 16 KB   -> 128 KB

    const int t = threadIdx.x;
    const size_t m0 = (size_t)blockIdx.x * 256;
    const int n0 = blockIdx.y * 128;
    const int w = t >> 6, lane = t & 63;
    const int wm = (w >> 1) * 64, wn = (w & 1) * 64;
    const int r16 = lane & 15, quad = lane >> 4;
    const int sw = r16 & 7;

    f32x4 ah[4][4] = {};
    f32x4 ag[4][4] = {};

    // staging quarters: 2 gll16 each
    auto stA = [&](int buf, int k0, int rbase) {       // rbase 0: rows 0-127, 2: rows 128-255
        #pragma unroll
        for (int r = rbase; r < rbase + 2; ++r) {
            int g = r * 512 + t; int row = g >> 3; int c8 = (g & 7) ^ (row & 7);
            gll16(Xbf + (m0 + row) * K + k0 + c8 * 8, &As[buf][g * 8]);
        }
    };
    auto stBh = [&](int buf, int k0) {
        #pragma unroll
        for (int r = 0; r < 2; ++r) {
            int g = r * 512 + t; int row = g >> 3; int c8 = (g & 7) ^ (row & 7);
            gll16(W + (size_t)(n0 + row) * K + k0 + c8 * 8, &Bh[buf][g * 8]);
        }
    };
    auto stBg = [&](int buf, int k0) {
        #pragma unroll
        for (int r = 0; r < 2; ++r) {
            int g = r * 512 + t; int row = g >> 3; int c8 = (g & 7) ^ (row & 7);
            gll16(W + (size_t)(512 + n0 + row) * K + k0 + c8 * 8, &Bg[buf][g * 8]);
        }
    };
    // register-fragment reads
    auto rdA = [&](bf16x8* d, int buf, int kg) {
        #pragma unroll
        for (int i = 0; i < 4; ++i)
            d[i] = *(const bf16x8*)&As[buf][(wm + i * 16 + r16) * 64 + (kg ^ sw) * 8];
    };
    auto rdBh = [&](bf16x8* d, int buf, int kg) {
        #pragma unroll
        for (int i = 0; i < 4; ++i)
            d[i] = *(const bf16x8*)&Bh[buf][(wn + i * 16 + r16) * 64 + (kg ^ sw) * 8];
    };
    auto rdBg = [&](bf16x8* d, int buf, int kg) {
        #pragma unroll
        for (int i = 0; i < 4; ++i)
            d[i] = *(const bf16x8*)&Bg[buf][(wn + i * 16 + r16) * 64 + (kg ^ sw) * 8];
    };
    auto mmH = [&](const bf16x8* af, const bf16x8* bb) {
        __builtin_amdgcn_s_setprio(1);
        #pragma unroll
        for (int mi = 0; mi < 4; ++mi)
            #pragma unroll
            for (int ni = 0; ni < 4; ++ni)
                ah[mi][ni] = MFMA16(af[mi], bb[ni], ah[mi][ni]);
        __builtin_amdgcn_s_setprio(0);
    };
    auto mmG = [&](const bf16x8* af, const bf16x8* bb) {
        __builtin_amdgcn_s_setprio(1);
        #pragma unroll
        for (int mi = 0; mi < 4; ++mi)
            #pragma unroll
            for (int ni = 0; ni < 4; ++ni)
                ag[mi][ni] = MFMA16(af[mi], bb[ni], ag[mi][ni]);
        __builtin_amdgcn_s_setprio(0);
    };

    // prologue: full tile 0 + A0 of tile 1 (pre-issues the P3-slot load)
    stA(0, 0, 0); stA(0, 0, 2); stBh(0, 0); stBg(0, 0);
    stA(1, 64, 0);
    asm volatile("s_waitcnt vmcnt(2)" ::: "memory");   // tile 0 landed; A0(1) in flight
    __builtin_amdgcn_s_barrier();

    #pragma unroll
    for (int tt = 0; tt < 8; ++tt) {
        const int cur = tt & 1, nxt = cur ^ 1;
        const int kn = (tt + 1) * 64;
        bf16x8 af[4], bhf[4], bgf[4];

        // ---- P0: kk=0, h ----
        rdA(af, cur, quad);
        rdBh(bhf, cur, quad);
        if (tt < 7) stA(nxt, kn, 2);                    // A1(t+1)
        if (tt < 7) { asm volatile("s_waitcnt vmcnt(4)" ::: "memory"); }
        else        { asm volatile("s_waitcnt vmcnt(0)" ::: "memory"); }
        __builtin_amdgcn_s_barrier();
        asm volatile("s_waitcnt lgkmcnt(0)" ::: "memory");
        mmH(af, bhf);
        __builtin_amdgcn_s_barrier();

        // ---- P1: kk=0, g (reuses af) ----
        rdBg(bgf, cur, quad);
        if (tt < 7) stBh(nxt, kn);
        __builtin_amdgcn_s_barrier();
        asm volatile("s_waitcnt lgkmcnt(0)" ::: "memory");
        mmG(af, bgf);
        __builtin_amdgcn_s_barrier();

        // ---- P2: kk=1, h ----
        rdA(af, cur, 4 + quad);
        rdBh(bhf, cur, 4 + quad);
        if (tt < 7) stBg(nxt, kn);
        __builtin_amdgcn_s_barrier();
        asm volatile("s_waitcnt lgkmcnt(0)" ::: "memory");
        mmH(af, bhf);
        __builtin_amdgcn_s_barrier();

        // ---- P3: kk=1, g ----
        rdBg(bgf, cur, 4 + quad);
        if (tt < 6) stA(cur, (tt + 2) * 64, 0);         // A0(t+2) -> buffer being retired
        if (tt < 6)      { asm volatile("s_waitcnt vmcnt(4)" ::: "memory"); }
        else if (tt == 6){ asm volatile("s_waitcnt vmcnt(2)" ::: "memory"); }
        __builtin_amdgcn_s_barrier();
        asm volatile("s_waitcnt lgkmcnt(0)" ::: "memory");
        mmG(af, bgf);
        __builtin_amdgcn_s_barrier();
    }

    // epilogue: z = sigmoid(gate); c = 1-z; v = z*g(hidden)
    #pragma unroll
    for (int mi = 0; mi < 4; ++mi)
        #pragma unroll
        for (int ni = 0; ni < 4; ++ni)
            #pragma unroll
            for (int r = 0; r < 4; ++r) {
                size_t row = m0 + wm + mi * 16 + quad * 4 + r;
                int col = n0 + wn + ni * 16 + r16;
                float hid = ah[mi][ni][r], gat = ag[mi][ni][r];
                float z = frcp(1.f + __expf(-gat));     // sigmoid(gate)
                float c = 1.f - z;                      // sigmoid(-gate)
                float gv = hid >= 0.f ? hid + 0.5f : frcp(1.f + __expf(-hid));
                CV[row * 512 + col] = packcv(c, z * gv);
            }
}

// ---------------- scan: h[t] = c[t]*h[t-1] + v[t], chunked 3-phase ----------------
#define NC 64
#define CHUNK 128  // 8192 / NC

__global__ __launch_bounds__(256) void scan1_kernel(
    const uint32_t* __restrict__ CV, float2* __restrict__ agg) {
    int idx = blockIdx.x * 256 + threadIdx.x;  // 8*64*512 = 262144
    int h = idx & 511;
    int ch = (idx >> 9) & (NC - 1);
    int b = idx >> 15;
    const uint32_t* p = CV + (((size_t)b * 8192 + (size_t)ch * CHUNK) * 512 + h);
    float C = 1.f, V = 0.f;
    for (int tt = 0; tt < CHUNK; tt += 8) {
        uint32_t u[8];
        #pragma unroll
        for (int j = 0; j < 8; ++j) u[j] = p[(size_t)(tt + j) * 512];
        #pragma unroll
        for (int j = 0; j < 8; ++j) {
            float c = bflo(u[j]), v = bfhi(u[j]);
            C *= c;
            V = c * V + v;
        }
    }
    agg[idx] = make_float2(C, V);
}

__global__ __launch_bounds__(256) void scan2_kernel(
    const float2* __restrict__ agg, float* __restrict__ h0) {
    int idx = blockIdx.x * 256 + threadIdx.x;  // 4096
    int h = idx & 511;
    int b = idx >> 9;
    float hr = 0.f;
    for (int ch = 0; ch < NC; ++ch) {
        size_t o = ((size_t)b * NC + ch) * 512 + h;
        h0[o] = hr;
        float2 a = agg[o];
        hr = a.x * hr + a.y;
    }
}

__global__ __launch_bounds__(256) void scan3_kernel(
    const uint32_t* __restrict__ CV, const float* __restrict__ h0,
    bf16* __restrict__ Hbf, float* __restrict__ hn) {
    int idx = blockIdx.x * 256 + threadIdx.x;
    int h = idx & 511;
    int ch = (idx >> 9) & (NC - 1);
    int b = idx >> 15;
    size_t base = ((size_t)b * 8192 + (size_t)ch * CHUNK) * 512 + h;
    const uint32_t* p = CV + base;
    bf16* q = Hbf + base;
    float hcur = h0[idx];
    for (int tt = 0; tt < CHUNK; tt += 8) {
        uint32_t u[8];
        #pragma unroll
        for (int j = 0; j < 8; ++j) u[j] = p[(size_t)(tt + j) * 512];
        #pragma unroll
        for (int j = 0; j < 8; ++j) {
            float c = bflo(u[j]), v = bfhi(u[j]);
            hcur = c * hcur + v;
            q[(size_t)(tt + j) * 512] = (bf16)hcur;
        }
    }
    if (ch == NC - 1) hn[b * 512 + h] = hcur;  // fp32 h_n output
}

// ---------------- GEMM2: out = h @ W_out^T (bf16 MFMA, fp32 out) ----------------
// Triple-buffered (144 KB LDS), 2 phases per K-tile, stages tile t+2,
// single counted vmcnt(6) per tile (6 loads always in flight).
__global__ __launch_bounds__(512, 2) void gemm2_kernel(
    const bf16* __restrict__ Ah, const bf16* __restrict__ Wo,
    float* __restrict__ Out) {
    constexpr int K = 512;
    __shared__ bf16 As[3][256 * 64];   // 96 KB
    __shared__ bf16 Bs[3][128 * 64];   // 48 KB -> 144 KB
    const int t = threadIdx.x;
    const size_t m0 = (size_t)blockIdx.x * 256;
    const int n0 = blockIdx.y * 128;
    const int w = t >> 6, lane = t & 63;
    const int wm = (w >> 1) * 64, wn = (w & 1) * 64;
    const int r16 = lane & 15, quad = lane >> 4;
    const int sw = r16 & 7;
    f32x4 acc[4][4] = {};

    auto stA = [&](int buf, int k0, int r0, int r1) {   // granule rows r0..r1-1 (of 4)
        #pragma unroll
        for (int r = r0; r < r1; ++r) {
            int g = r * 512 + t; int row = g >> 3; int c8 = (g & 7) ^ (row & 7);
            gll16(Ah + (m0 + row) * K + k0 + c8 * 8, &As[buf][g * 8]);
        }
    };
    auto stB = [&](int buf, int k0) {
        #pragma unroll
        for (int r = 0; r < 2; ++r) {
            int g = r * 512 + t; int row = g >> 3; int c8 = (g & 7) ^ (row & 7);
            gll16(Wo + (size_t)(n0 + row) * K + k0 + c8 * 8, &Bs[buf][g * 8]);
        }
    };
    auto rdA = [&](bf16x8* d, int buf, int kg) {
        #pragma unroll
        for (int i = 0; i < 4; ++i)
            d[i] = *(const bf16x8*)&As[buf][(wm + i * 16 + r16) * 64 + (kg ^ sw) * 8];
    };
    auto rdB = [&](bf16x8* d, int buf, int kg) {
        #pragma unroll
        for (int i = 0; i < 4; ++i)
            d[i] = *(const bf16x8*)&Bs[buf][(wn + i * 16 + r16) * 64 + (kg ^ sw) * 8];
    };
    auto mm = [&](const bf16x8* af, const bf16x8* bb) {
        __builtin_amdgcn_s_setprio(1);
        #pragma unroll
        for (int mi = 0; mi < 4; ++mi)
            #pragma unroll
            for (int ni = 0; ni < 4; ++ni)
                acc[mi][ni] = MFMA16(af[mi], bb[ni], acc[mi][ni]);
        __builtin_amdgcn_s_setprio(0);
    };

    // prologue: tiles 0 and 1 fully staged; wait tile 0 only
    stA(0, 0, 0, 4); stB(0, 0);
    stA(1, 64, 0, 4); stB(1, 64);
    asm volatile("s_waitcnt vmcnt(6)" ::: "memory");
    __builtin_amdgcn_s_barrier();

    #pragma unroll
    for (int tt = 0; tt < 8; ++tt) {
        const int cur = tt % 3, n2 = (tt + 2) % 3;
        const int k2 = (tt + 2) * 64;
        bf16x8 af[4], bff[4];

        // ---- P0: kk=0 ----
        rdA(af, cur, quad);
        rdB(bff, cur, quad);
        if (tt < 6) stA(n2, k2, 0, 3);                  // 3 loads of tile t+2
        __builtin_amdgcn_s_barrier();
        asm volatile("s_waitcnt lgkmcnt(0)" ::: "memory");
        mm(af, bff);
        __builtin_amdgcn_s_barrier();

        // ---- P1: kk=1 ----
        rdA(af, cur, 4 + quad);
        rdB(bff, cur, 4 + quad);
        if (tt < 6) { stA(n2, k2, 3, 4); stB(n2, k2); } // remaining 3 loads
        if (tt < 6)      { asm volatile("s_waitcnt vmcnt(6)" ::: "memory"); }
        else if (tt == 6){ asm volatile("s_waitcnt vmcnt(0)" ::: "memory"); }
        __builtin_amdgcn_s_barrier();
        asm volatile("s_waitcnt lgkmcnt(0)" ::: "memory");
        mm(af, bff);
        __builtin_amdgcn_s_barrier();
    }

    #pragma unroll
    for (int mi = 0; mi < 4; ++mi)
        #pragma unroll
        for (int ni = 0; ni < 4; ++ni)
            #pragma unroll
            for (int r = 0; r < 4; ++r) {
                size_t row = m0 + wm + mi * 16 + quad * 4 + r;
                int col = n0 + wn + ni * 16 + r16;
                Out[row * 512 + col] = acc[mi][ni][r];
            }
}

extern "C" void kernel_launch(void* const* d_in, const int* in_sizes, int n_in,
                              void* d_out, int out_size, void* d_ws, size_t ws_size,
                              hipStream_t stream) {
    const float* x    = (const float*)d_in[0];
    // d_in[1] = is_init (unused by reference)
    const float* Whg  = (const float*)d_in[2];
    const float* Wout = (const float*)d_in[3];
    float* out = (float*)d_out;

    const int M = 8 * 8192;  // 65536

    // Workspace layout (total 206045184 B):
    //   [0, 67108864)           Xbf  (later aliased by Hbf — Xbf dead after gemm1)
    //   [67108864, 68157440)    Whg_bf
    //   [68157440, 68681728)    Wout_bf
    //   [68681728, 202899456)   CV
    //   [202899456, 204996608)  agg
    //   [204996608, 206045184)  h0
    char* ws = (char*)d_ws;
    bf16*     Xbf     = (bf16*)ws;
    bf16*     Hbf     = (bf16*)ws;                 // alias: valid, see ordering
    bf16*     Whg_bf  = (bf16*)(ws + 67108864);
    bf16*     Wout_bf = (bf16*)(ws + 68157440);
    uint32_t* CV      = (uint32_t*)(ws + 68681728);
    float2*   agg     = (float2*)(ws + 202899456);
    float*    h0      = (float*)(ws + 204996608);

    conv_kernel<<<33536, 256, 0, stream>>>(x, Whg, Wout, Xbf, Whg_bf, Wout_bf);

    dim3 g1(M / 256, 4);
    gemm1_kernel<<<g1, 512, 0, stream>>>(Xbf, Whg_bf, CV);

    scan1_kernel<<<(8 * NC * 512) / 256, 256, 0, stream>>>(CV, agg);
    scan2_kernel<<<16, 256, 0, stream>>>(agg, h0);
    scan3_kernel<<<(8 * NC * 512) / 256, 256, 0, stream>>>(CV, h0, Hbf,
                                                           out + (size_t)M * 512);

    dim3 g2(M / 256, 4);
    gemm2_kernel<<<g2, 512, 0, stream>>>(Hbf, Wout_bf, out);
}

// Round 3
// 400.588 us; speedup vs baseline: 1.2657x; 1.0864x over previous
//
#include <hip/hip_runtime.h>
#include <stdint.h>

typedef __bf16 bf16;
typedef bf16 bf16x8 __attribute__((ext_vector_type(8)));
typedef bf16 bf16x4 __attribute__((ext_vector_type(4)));
typedef float f32x4 __attribute__((ext_vector_type(4)));

#define MFMA16(a, b, c) __builtin_amdgcn_mfma_f32_16x16x32_bf16(a, b, c, 0, 0, 0)

__device__ __forceinline__ void gll16(const void* g, void* l) {
    __builtin_amdgcn_global_load_lds(
        (const __attribute__((address_space(1))) void*)g,
        (__attribute__((address_space(3))) void*)l, 16, 0, 0);
}

__device__ __forceinline__ float frcp(float x) { return __builtin_amdgcn_rcpf(x); }

__device__ __forceinline__ float bflo(uint32_t u) {
    union { uint32_t i; float f; } x; x.i = u << 16; return x.f;
}
__device__ __forceinline__ float bfhi(uint32_t u) {
    union { uint32_t i; float f; } x; x.i = u & 0xffff0000u; return x.f;
}
__device__ __forceinline__ uint32_t packcv(float c, float v) {
    union { bf16 b[2]; uint32_t u; } p;
    p.b[0] = (bf16)c; p.b[1] = (bf16)v; return p.u;
}

// ---------------- fp32 -> bf16 conversion: X + Whg + Wout ----------------
__global__ __launch_bounds__(256) void conv_kernel(
    const float* __restrict__ X, const float* __restrict__ Whg,
    const float* __restrict__ Wout, bf16* __restrict__ Xbf,
    bf16* __restrict__ Whg_bf, bf16* __restrict__ Wout_bf) {
    int i = blockIdx.x * 256 + threadIdx.x;
    if (i < 8388608) {
        f32x4 v = ((const f32x4*)X)[i];
        ((bf16x4*)Xbf)[i] = __builtin_convertvector(v, bf16x4);
    } else if (i < 8388608 + 131072) {
        int j = i - 8388608;
        f32x4 v = ((const f32x4*)Whg)[j];
        ((bf16x4*)Whg_bf)[j] = __builtin_convertvector(v, bf16x4);
    } else {
        int j = i - (8388608 + 131072);  // < 65536
        f32x4 v = ((const f32x4*)Wout)[j];
        ((bf16x4*)Wout_bf)[j] = __builtin_convertvector(v, bf16x4);
    }
}

// ---------------- GEMM1: hg = x @ W_hg^T, fused sigmoid epilogue + fused scan1 ----------------
// m201-style 4-phase schedule (see R2), counted vmcnt, double-buffered 128 KB LDS.
// NEW: (a) XCD-chunked block swizzle: each XCD owns 32 contiguous M-panels; the 4
//      N-blocks sharing an X panel are time-adjacent on the same XCD L2.
//      (b) scan1 fused into the epilogue: block = 2 chunks x 128 cols; per-chunk
//      affine aggregate (C, V) computed via ordered quad-butterfly + LDS cross-wave
//      combine, written straight to agg. scan1 kernel eliminated.
__global__ __launch_bounds__(512, 2) void gemm1_kernel(
    const bf16* __restrict__ Xbf, const bf16* __restrict__ W,
    uint32_t* __restrict__ CV, float2* __restrict__ agg) {
    constexpr int K = 512;
    __shared__ bf16 As[2][256 * 64];   // 2 x 32 KB
    __shared__ bf16 Bh[2][128 * 64];   // 2 x 16 KB
    __shared__ bf16 Bg[2][128 * 64];   // 2 x 16 KB   -> 128 KB

    const int t = threadIdx.x;
    // XCD-chunked swizzle: lin = (m_local*4 + n)*8 + xcd  (1024 = 8 XCD x 128)
    const int lin = blockIdx.x;
    const int xcd = lin & 7, j = lin >> 3;
    const size_t m0 = (size_t)(xcd * 32 + (j >> 2)) * 256;
    const int n0 = (j & 3) * 128;
    const int w = t >> 6, lane = t & 63;
    const int wm = (w >> 1) * 64, wn = (w & 1) * 64;
    const int r16 = lane & 15, quad = lane >> 4;
    const int sw = r16 & 7;

    f32x4 ah[4][4] = {};
    f32x4 ag[4][4] = {};

    auto stA = [&](int buf, int k0, int rbase) {
        #pragma unroll
        for (int r = rbase; r < rbase + 2; ++r) {
            int g = r * 512 + t; int row = g >> 3; int c8 = (g & 7) ^ (row & 7);
            gll16(Xbf + (m0 + row) * K + k0 + c8 * 8, &As[buf][g * 8]);
        }
    };
    auto stBh = [&](int buf, int k0) {
        #pragma unroll
        for (int r = 0; r < 2; ++r) {
            int g = r * 512 + t; int row = g >> 3; int c8 = (g & 7) ^ (row & 7);
            gll16(W + (size_t)(n0 + row) * K + k0 + c8 * 8, &Bh[buf][g * 8]);
        }
    };
    auto stBg = [&](int buf, int k0) {
        #pragma unroll
        for (int r = 0; r < 2; ++r) {
            int g = r * 512 + t; int row = g >> 3; int c8 = (g & 7) ^ (row & 7);
            gll16(W + (size_t)(512 + n0 + row) * K + k0 + c8 * 8, &Bg[buf][g * 8]);
        }
    };
    auto rdA = [&](bf16x8* d, int buf, int kg) {
        #pragma unroll
        for (int i = 0; i < 4; ++i)
            d[i] = *(const bf16x8*)&As[buf][(wm + i * 16 + r16) * 64 + (kg ^ sw) * 8];
    };
    auto rdBh = [&](bf16x8* d, int buf, int kg) {
        #pragma unroll
        for (int i = 0; i < 4; ++i)
            d[i] = *(const bf16x8*)&Bh[buf][(wn + i * 16 + r16) * 64 + (kg ^ sw) * 8];
    };
    auto rdBg = [&](bf16x8* d, int buf, int kg) {
        #pragma unroll
        for (int i = 0; i < 4; ++i)
            d[i] = *(const bf16x8*)&Bg[buf][(wn + i * 16 + r16) * 64 + (kg ^ sw) * 8];
    };
    auto mmH = [&](const bf16x8* af, const bf16x8* bb) {
        __builtin_amdgcn_s_setprio(1);
        #pragma unroll
        for (int mi = 0; mi < 4; ++mi)
            #pragma unroll
            for (int ni = 0; ni < 4; ++ni)
                ah[mi][ni] = MFMA16(af[mi], bb[ni], ah[mi][ni]);
        __builtin_amdgcn_s_setprio(0);
    };
    auto mmG = [&](const bf16x8* af, const bf16x8* bb) {
        __builtin_amdgcn_s_setprio(1);
        #pragma unroll
        for (int mi = 0; mi < 4; ++mi)
            #pragma unroll
            for (int ni = 0; ni < 4; ++ni)
                ag[mi][ni] = MFMA16(af[mi], bb[ni], ag[mi][ni]);
        __builtin_amdgcn_s_setprio(0);
    };

    // prologue: full tile 0 + A0 of tile 1
    stA(0, 0, 0); stA(0, 0, 2); stBh(0, 0); stBg(0, 0);
    stA(1, 64, 0);
    asm volatile("s_waitcnt vmcnt(2)" ::: "memory");
    __builtin_amdgcn_s_barrier();

    #pragma unroll
    for (int tt = 0; tt < 8; ++tt) {
        const int cur = tt & 1, nxt = cur ^ 1;
        const int kn = (tt + 1) * 64;
        bf16x8 af[4], bhf[4], bgf[4];

        // ---- P0: kk=0, h ----
        rdA(af, cur, quad);
        rdBh(bhf, cur, quad);
        if (tt < 7) stA(nxt, kn, 2);
        if (tt < 7) { asm volatile("s_waitcnt vmcnt(4)" ::: "memory"); }
        else        { asm volatile("s_waitcnt vmcnt(0)" ::: "memory"); }
        __builtin_amdgcn_s_barrier();
        asm volatile("s_waitcnt lgkmcnt(0)" ::: "memory");
        mmH(af, bhf);
        __builtin_amdgcn_s_barrier();

        // ---- P1: kk=0, g (reuses af) ----
        rdBg(bgf, cur, quad);
        if (tt < 7) stBh(nxt, kn);
        __builtin_amdgcn_s_barrier();
        asm volatile("s_waitcnt lgkmcnt(0)" ::: "memory");
        mmG(af, bgf);
        __builtin_amdgcn_s_barrier();

        // ---- P2: kk=1, h ----
        rdA(af, cur, 4 + quad);
        rdBh(bhf, cur, 4 + quad);
        if (tt < 7) stBg(nxt, kn);
        __builtin_amdgcn_s_barrier();
        asm volatile("s_waitcnt lgkmcnt(0)" ::: "memory");
        mmH(af, bhf);
        __builtin_amdgcn_s_barrier();

        // ---- P3: kk=1, g ----
        rdBg(bgf, cur, 4 + quad);
        if (tt < 6) stA(cur, (tt + 2) * 64, 0);
        if (tt < 6)      { asm volatile("s_waitcnt vmcnt(4)" ::: "memory"); }
        else if (tt == 6){ asm volatile("s_waitcnt vmcnt(2)" ::: "memory"); }
        __builtin_amdgcn_s_barrier();
        asm volatile("s_waitcnt lgkmcnt(0)" ::: "memory");
        mmG(af, bgf);
        __builtin_amdgcn_s_barrier();
    }

    // ---- epilogue: sigmoid + pack CV, fused per-chunk scan aggregate ----
    // chunk = 128 rows; block = chunks ch0 (rows 0-127) and ch0+1 (rows 128-255).
    // Affine combine rule (later o earlier): C = Cl*Ce, V = Cl*Ve + Vl.
    float2* red = (float2*)&As[0][0];   // 8 waves x 64 cols, 4 KB (LDS reuse)

    #pragma unroll
    for (int ni = 0; ni < 4; ++ni) {
        float Cw = 1.f, Vw = 0.f;       // wave-local 64-row running aggregate
        #pragma unroll
        for (int mi = 0; mi < 4; ++mi) {
            float C4 = 1.f, V4 = 0.f;   // this thread's 4 rows (quad*4 + r)
            #pragma unroll
            for (int r = 0; r < 4; ++r) {
                size_t row = m0 + wm + mi * 16 + quad * 4 + r;
                int col = n0 + wn + ni * 16 + r16;
                float hid = ah[mi][ni][r], gat = ag[mi][ni][r];
                float z = frcp(1.f + __expf(-gat));     // sigmoid(gate)
                float c = 1.f - z;                      // sigmoid(-gate)
                float gv = hid >= 0.f ? hid + 0.5f : frcp(1.f + __expf(-hid));
                float v = z * gv;
                CV[row * 512 + col] = packcv(c, v);
                V4 = c * V4 + v;
                C4 *= c;
            }
            // ordered combine across quads (rows quad*4..quad*4+3, ascending quad)
            float Cp = __shfl_xor(C4, 16), Vp = __shfl_xor(V4, 16);
            float Cn = C4 * Cp;
            float Vn = (quad & 1) ? (C4 * Vp + V4) : (Cp * V4 + Vp);
            float Cq = __shfl_xor(Cn, 32), Vq = __shfl_xor(Vn, 32);
            float C16 = Cn * Cq;
            float V16 = (quad & 2) ? (Cn * Vq + Vn) : (Cq * Vn + Vq);
            Vw = C16 * Vw + V16;
            Cw *= C16;
        }
        red[w * 64 + ni * 16 + r16] = make_float2(Cw, Vw);
    }
    asm volatile("s_waitcnt lgkmcnt(0)" ::: "memory");
    __builtin_amdgcn_s_barrier();
    asm volatile("" ::: "memory");
    if ((w & 2) == 0) {                 // waves 0,1,4,5 finalize
        float2 e = red[w * 64 + lane];        // earlier 64 rows (wm = 0 / 128)
        float2 l = red[(w + 2) * 64 + lane];  // later 64 rows  (wm = 64 / 192)
        int b = (int)(m0 >> 13);
        int ch = (int)((m0 & 8191) >> 7) + (w >> 2);
        int col = n0 + (w & 1) * 64 + lane;
        agg[((size_t)b * 64 + ch) * 512 + col] =
            make_float2(l.x * e.x, l.x * e.y + l.y);
    }
}

// ---------------- scan: h[t] = c[t]*h[t-1] + v[t] ----------------
#define NC 64
#define CHUNK 128  // 8192 / NC

__global__ __launch_bounds__(256) void scan2_kernel(
    const float2* __restrict__ agg, float* __restrict__ h0) {
    int idx = blockIdx.x * 256 + threadIdx.x;  // 4096
    int h = idx & 511;
    int b = idx >> 9;
    float hr = 0.f;
    for (int ch = 0; ch < NC; ++ch) {
        size_t o = ((size_t)b * NC + ch) * 512 + h;
        h0[o] = hr;
        float2 a = agg[o];
        hr = a.x * hr + a.y;
    }
}

__global__ __launch_bounds__(256) void scan3_kernel(
    const uint32_t* __restrict__ CV, const float* __restrict__ h0,
    bf16* __restrict__ Hbf, float* __restrict__ hn) {
    int idx = blockIdx.x * 256 + threadIdx.x;
    int h = idx & 511;
    int ch = (idx >> 9) & (NC - 1);
    int b = idx >> 15;
    size_t base = ((size_t)b * 8192 + (size_t)ch * CHUNK) * 512 + h;
    const uint32_t* p = CV + base;
    bf16* q = Hbf + base;
    float hcur = h0[idx];
    for (int tt = 0; tt < CHUNK; tt += 8) {
        uint32_t u[8];
        #pragma unroll
        for (int j = 0; j < 8; ++j) u[j] = p[(size_t)(tt + j) * 512];
        #pragma unroll
        for (int j = 0; j < 8; ++j) {
            float c = bflo(u[j]), v = bfhi(u[j]);
            hcur = c * hcur + v;
            q[(size_t)(tt + j) * 512] = (bf16)hcur;
        }
    }
    if (ch == NC - 1) hn[b * 512 + h] = hcur;  // fp32 h_n output
}

// ---------------- GEMM2: out = h @ W_out^T (bf16 MFMA, fp32 out) ----------------
// Triple-buffered (144 KB LDS), 2 phases per K-tile, stages tile t+2,
// counted vmcnt(6). XCD-chunked swizzle (same as gemm1).
__global__ __launch_bounds__(512, 2) void gemm2_kernel(
    const bf16* __restrict__ Ah, const bf16* __restrict__ Wo,
    float* __restrict__ Out) {
    constexpr int K = 512;
    __shared__ bf16 As[3][256 * 64];   // 96 KB
    __shared__ bf16 Bs[3][128 * 64];   // 48 KB -> 144 KB
    const int t = threadIdx.x;
    const int lin = blockIdx.x;
    const int xcd = lin & 7, j = lin >> 3;
    const size_t m0 = (size_t)(xcd * 32 + (j >> 2)) * 256;
    const int n0 = (j & 3) * 128;
    const int w = t >> 6, lane = t & 63;
    const int wm = (w >> 1) * 64, wn = (w & 1) * 64;
    const int r16 = lane & 15, quad = lane >> 4;
    const int sw = r16 & 7;
    f32x4 acc[4][4] = {};

    auto stA = [&](int buf, int k0, int r0, int r1) {
        #pragma unroll
        for (int r = r0; r < r1; ++r) {
            int g = r * 512 + t; int row = g >> 3; int c8 = (g & 7) ^ (row & 7);
            gll16(Ah + (m0 + row) * K + k0 + c8 * 8, &As[buf][g * 8]);
        }
    };
    auto stB = [&](int buf, int k0) {
        #pragma unroll
        for (int r = 0; r < 2; ++r) {
            int g = r * 512 + t; int row = g >> 3; int c8 = (g & 7) ^ (row & 7);
            gll16(Wo + (size_t)(n0 + row) * K + k0 + c8 * 8, &Bs[buf][g * 8]);
        }
    };
    auto rdA = [&](bf16x8* d, int buf, int kg) {
        #pragma unroll
        for (int i = 0; i < 4; ++i)
            d[i] = *(const bf16x8*)&As[buf][(wm + i * 16 + r16) * 64 + (kg ^ sw) * 8];
    };
    auto rdB = [&](bf16x8* d, int buf, int kg) {
        #pragma unroll
        for (int i = 0; i < 4; ++i)
            d[i] = *(const bf16x8*)&Bs[buf][(wn + i * 16 + r16) * 64 + (kg ^ sw) * 8];
    };
    auto mm = [&](const bf16x8* af, const bf16x8* bb) {
        __builtin_amdgcn_s_setprio(1);
        #pragma unroll
        for (int mi = 0; mi < 4; ++mi)
            #pragma unroll
            for (int ni = 0; ni < 4; ++ni)
                acc[mi][ni] = MFMA16(af[mi], bb[ni], acc[mi][ni]);
        __builtin_amdgcn_s_setprio(0);
    };

    stA(0, 0, 0, 4); stB(0, 0);
    stA(1, 64, 0, 4); stB(1, 64);
    asm volatile("s_waitcnt vmcnt(6)" ::: "memory");
    __builtin_amdgcn_s_barrier();

    #pragma unroll
    for (int tt = 0; tt < 8; ++tt) {
        const int cur = tt % 3, n2 = (tt + 2) % 3;
        const int k2 = (tt + 2) * 64;
        bf16x8 af[4], bff[4];

        // ---- P0: kk=0 ----
        rdA(af, cur, quad);
        rdB(bff, cur, quad);
        if (tt < 6) stA(n2, k2, 0, 3);
        __builtin_amdgcn_s_barrier();
        asm volatile("s_waitcnt lgkmcnt(0)" ::: "memory");
        mm(af, bff);
        __builtin_amdgcn_s_barrier();

        // ---- P1: kk=1 ----
        rdA(af, cur, 4 + quad);
        rdB(bff, cur, 4 + quad);
        if (tt < 6) { stA(n2, k2, 3, 4); stB(n2, k2); }
        if (tt < 6)      { asm volatile("s_waitcnt vmcnt(6)" ::: "memory"); }
        else if (tt == 6){ asm volatile("s_waitcnt vmcnt(0)" ::: "memory"); }
        __builtin_amdgcn_s_barrier();
        asm volatile("s_waitcnt lgkmcnt(0)" ::: "memory");
        mm(af, bff);
        __builtin_amdgcn_s_barrier();
    }

    #pragma unroll
    for (int mi = 0; mi < 4; ++mi)
        #pragma unroll
        for (int ni = 0; ni < 4; ++ni)
            #pragma unroll
            for (int r = 0; r < 4; ++r) {
                size_t row = m0 + wm + mi * 16 + quad * 4 + r;
                int col = n0 + wn + ni * 16 + r16;
                Out[row * 512 + col] = acc[mi][ni][r];
            }
}

extern "C" void kernel_launch(void* const* d_in, const int* in_sizes, int n_in,
                              void* d_out, int out_size, void* d_ws, size_t ws_size,
                              hipStream_t stream) {
    const float* x    = (const float*)d_in[0];
    // d_in[1] = is_init (unused by reference)
    const float* Whg  = (const float*)d_in[2];
    const float* Wout = (const float*)d_in[3];
    float* out = (float*)d_out;

    const int M = 8 * 8192;  // 65536

    // Workspace layout (total 206045184 B):
    //   [0, 67108864)           Xbf  (later aliased by Hbf — Xbf dead after gemm1)
    //   [67108864, 68157440)    Whg_bf
    //   [68157440, 68681728)    Wout_bf
    //   [68681728, 202899456)   CV
    //   [202899456, 204996608)  agg
    //   [204996608, 206045184)  h0
    char* ws = (char*)d_ws;
    bf16*     Xbf     = (bf16*)ws;
    bf16*     Hbf     = (bf16*)ws;                 // alias: valid, see ordering
    bf16*     Whg_bf  = (bf16*)(ws + 67108864);
    bf16*     Wout_bf = (bf16*)(ws + 68157440);
    uint32_t* CV      = (uint32_t*)(ws + 68681728);
    float2*   agg     = (float2*)(ws + 202899456);
    float*    h0      = (float*)(ws + 204996608);

    conv_kernel<<<33536, 256, 0, stream>>>(x, Whg, Wout, Xbf, Whg_bf, Wout_bf);

    gemm1_kernel<<<1024, 512, 0, stream>>>(Xbf, Whg_bf, CV, agg);

    scan2_kernel<<<16, 256, 0, stream>>>(agg, h0);
    scan3_kernel<<<(8 * NC * 512) / 256, 256, 0, stream>>>(CV, h0, Hbf,
                                                           out + (size_t)M * 512);

    gemm2_kernel<<<1024, 512, 0, stream>>>(Hbf, Wout_bf, out);
}